// Round 10
// baseline (801.516 us; speedup 1.0000x reference)
//
#include <hip/hip_runtime.h>
#include <math.h>

#define NNODES 100000
#define NEDGES 200000
#define HD 64
#define NP2 250000
#define NP3 500000
#define NG 2048
#define NCLS 10
#define NFEAT 18
#define EFEAT 18

typedef short short8v __attribute__((ext_vector_type(8)));
typedef float f32x4 __attribute__((ext_vector_type(4)));

__device__ __forceinline__ unsigned short bf16r(float a) {
    unsigned u = __builtin_bit_cast(unsigned, a);
    return (unsigned short)((u + 0x7FFFu + ((u >> 16) & 1u)) >> 16);
}

#define LOG2E 1.4426950408889634f

// ---------------------------------------------------------------------------
// Fused prep + encode + zeroing (one dispatch).  Unchanged from R8.
// ---------------------------------------------------------------------------
#define NB_ENC (((NNODES + NEDGES) * 64 + 255) / 256)

__global__ void prep_encode(const float* __restrict__ X, const float* __restrict__ Wf,
                            const float* __restrict__ bf,
                            const float* __restrict__ Ea, const float* __restrict__ Wb,
                            const float* __restrict__ bb,
                            float* __restrict__ W0, unsigned short* __restrict__ W0b,
                            unsigned short* __restrict__ eab,
                            const float* __restrict__ w_ih, const float* __restrict__ w_hh,
                            const float* __restrict__ b_ih, const float* __restrict__ b_hh,
                            unsigned short* __restrict__ Bp, float* __restrict__ bsum,
                            float* __restrict__ zsmall, float* __restrict__ hzero,
                            float* __restrict__ pooled) {
    int b = blockIdx.x;
    int t = threadIdx.x;
    if (b < NB_ENC) {
        long gid = (long)b * 256 + t;
        if (gid >= (long)(NNODES + NEDGES) * 64) return;
        long r = gid >> 6;
        int col = (int)(gid & 63);
        if (r < NNODES) {
            float acc = bf[col];
            const float* xr = X + r * NFEAT;
            for (int k = 0; k < NFEAT; ++k) acc += xr[k] * Wf[k * 64 + col];
            W0[gid] = acc;
            W0b[gid] = bf16r(acc);
        } else {
            long r2 = r - NNODES;
            float acc = bb[col];
            const float* xr = Ea + r2 * EFEAT;
            for (int k = 0; k < EFEAT; ++k) acc += xr[k] * Wb[k * 64 + col];
            eab[r2 * 64 + col] = bf16r(acc);
        }
    } else if (b < NB_ENC + 192) {
        int gid = (b - NB_ENC) * 256 + t;
        int kc = gid >> 13;
        int rem = gid & 8191;
        int nt = rem >> 9;
        int rem2 = rem & 511;
        int l = rem2 >> 3, j = rem2 & 7;
        int c = l & 15, q = l >> 4;
        int jh = nt >> 2, qg = nt & 3;
        int k = kc * 32 + q * 8 + j;
        int n = qg * 64 + 16 * jh + c;
        float f = (k < 128) ? w_ih[n * 128 + k] : w_hh[n * 64 + (k - 128)];
        float s = (qg == 2) ? 2.f * LOG2E : LOG2E;
        Bp[gid] = bf16r(f * s);
    } else if (b == NB_ENC + 192) {
        float s = ((t >> 6) == 2) ? 2.f * LOG2E : LOG2E;
        bsum[t] = (b_ih[t] + b_hh[t]) * s;
        for (int i = t; i < 960; i += 256) zsmall[i] = 0.f;
    } else if (b < NB_ENC + 193 + 3200) {
        long base = ((long)(b - NB_ENC - 193) * 256 + t) * 16;
        f32x4 z = {0.f, 0.f, 0.f, 0.f};
        f32x4* p = (f32x4*)(hzero + base);
        long lim = 2L * NNODES * 64;
        if (base + 16 <= lim) { p[0] = z; p[1] = z; p[2] = z; p[3] = z; }
    } else {
        pooled[(b - NB_ENC - 193 - 3200) * 256 + t] = 0.f;
    }
}

// ---------------------------------------------------------------------------
// Per-NODE LSTM step-0: h0,c0 = f(x_enc[node]).  Step 0 sees zero edge/h/c,
// so it is a pure function of the conv's INPUT ENCODING for that node —
// computed once per node instead of once per path (7.5x redundancy).
// NOTE: the input encoding differs per conv (conv1: W0b, conv2: Winb), so
// this kernel runs once per conv with the matching xb (R9's bug: ran once
// with W0b and fed conv2 with it -> absmax 0.125).
// h0b: bf16 (same rounding h always had via the LDS handoff); c0: f32
// (exact — numerics identical to the old in-register path).
// ---------------------------------------------------------------------------
__global__ __launch_bounds__(256)
void init_state(const unsigned short* __restrict__ xb,
                const unsigned short* __restrict__ Bp, const float* __restrict__ bsum,
                unsigned short* __restrict__ h0b, float* __restrict__ c0) {
    __shared__ unsigned short Al[64 * 200];
    const int t = threadIdx.x;
    const int w = t >> 6, lane = t & 63;
    const int c = lane & 15, q = lane >> 4;
    const int pl = t >> 2, gq = t & 3;
    const int r0 = blockIdx.x * 64;
    const short8v* __restrict__ Bv = (const short8v*)Bp;
    const int bbase = w * 256 + lane;

    {
        int row = r0 + pl;
        if (row >= NNODES) row = NNODES - 1;
        const uint4* s4 = (const uint4*)(xb + (size_t)row * HD);
        *(uint4*)&Al[pl * 200 + gq * 16] = s4[2 * gq];
        *(uint4*)&Al[pl * 200 + gq * 16 + 8] = s4[2 * gq + 1];
    }
    float breg[4];
#pragma unroll
    for (int g2 = 0; g2 < 4; ++g2) breg[g2] = bsum[g2 * 64 + 16 * w + c];
    __syncthreads();

    short8v b0[4], b1[4];
#pragma unroll
    for (int g2 = 0; g2 < 4; ++g2) {
        b0[g2] = Bv[g2 * 64 + bbase];
        b1[g2] = Bv[1024 + g2 * 64 + bbase];
    }
    f32x4 acc[4][4];
#pragma unroll
    for (int mt = 0; mt < 4; ++mt)
#pragma unroll
        for (int g2 = 0; g2 < 4; ++g2) {
            f32x4 v; v[0] = breg[g2]; v[1] = breg[g2]; v[2] = breg[g2]; v[3] = breg[g2];
            acc[mt][g2] = v;
        }
#pragma unroll
    for (int mt = 0; mt < 4; ++mt) {
        short8v af = *(const short8v*)&Al[(mt * 16 + c) * 200 + q * 8];
#pragma unroll
        for (int g2 = 0; g2 < 4; ++g2)
            acc[mt][g2] = __builtin_amdgcn_mfma_f32_16x16x32_bf16(af, b0[g2], acc[mt][g2], 0, 0, 0);
    }
#pragma unroll
    for (int mt = 0; mt < 4; ++mt) {
        short8v af = *(const short8v*)&Al[(mt * 16 + c) * 200 + 32 + q * 8];
#pragma unroll
        for (int g2 = 0; g2 < 4; ++g2)
            acc[mt][g2] = __builtin_amdgcn_mfma_f32_16x16x32_bf16(af, b1[g2], acc[mt][g2], 0, 0, 0);
    }

#pragma unroll
    for (int mt = 0; mt < 4; ++mt) {
#pragma unroll
        for (int r = 0; r < 4; ++r) {
            float gi = acc[mt][0][r], gf = acc[mt][1][r];
            float gg = acc[mt][2][r], go = acc[mt][3][r];
            float ea = __builtin_amdgcn_exp2f(-gf);
            float eb = __builtin_amdgcn_exp2f(-gi);
            float ed = __builtin_amdgcn_exp2f(-gg);
            float eo = __builtin_amdgcn_exp2f(-go);
            float pa = 1.f + ea, pb = 1.f + eb, pd = 1.f + ed;
            float cn = ((1.f - ed) * pa) * __builtin_amdgcn_rcpf(pa * pb * pd);
            float et = __builtin_amdgcn_exp2f(-2.8853900817779268f * cn);
            float hn = (1.f - et) * __builtin_amdgcn_rcpf((1.f + eo) * (1.f + et));
            int node = r0 + mt * 16 + q * 4 + r;
            if (node < NNODES) {
                h0b[(size_t)node * HD + 16 * w + c] = bf16r(hn);
                c0[(size_t)node * HD + 16 * w + c] = cn;
            }
        }
    }
}

// ---------------------------------------------------------------------------
// MFMA LSTM path conv — R8's verified inner loop (3-slot B stream, mid-MFMA
// gathers, lastnode staging, double-buffered LDS, 3 blk/CU), with step 0
// hoisted to init_state: prologue gathers x1/e0/h0 rows into LDS and the
// initial cell state c0 into creg; the loop runs only full steps 1..L-1.
// conv<2> collapses to a single step (no in-loop barrier).
// DO NOT TOUCH the stream/gather schedule (R2/R3/R6 regressions).
// ---------------------------------------------------------------------------
template <int L>
__global__ __launch_bounds__(256, 3)
void conv_mfma(const unsigned short* __restrict__ xb, const unsigned short* __restrict__ eab,
               const unsigned short* __restrict__ h0b, const float* __restrict__ c0,
               const int* __restrict__ paths, const int* __restrict__ ei,
               const unsigned short* __restrict__ Bp, const float* __restrict__ bsum,
               float* __restrict__ hsum, int P) {
    __shared__ unsigned short Al[2][64 * 200];
    __shared__ int lastnode_s[64];
    __shared__ int firstnode_s[64];

    const int t = threadIdx.x;
    const int w = t >> 6, lane = t & 63;
    const int c = lane & 15, q = lane >> 4;
    const int pl = t >> 2, gq = t & 3;
    const long pg = (long)blockIdx.x * 64 + pl;
    const int pc = (pg < P) ? (int)pg : P - 1;

    const short8v* __restrict__ Bv = (const short8v*)Bp;
    const int bbase = w * 256 + lane;

    float breg[4];
#pragma unroll
    for (int g2 = 0; g2 < 4; ++g2) breg[g2] = bsum[g2 * 64 + 16 * w + c];

    float creg[16];
    f32x4 acc[4][4];
    short8v bs0[4], bs1[4], bs2[4];
    uint4 nu0, nu1, ev0, ev1;

    // ---- prologue: gather x1 / e0 / h0 rows into buffer 0; stage indices
    {
        int n0 = paths[pc * L + 0];
        int n1 = paths[pc * L + 1];
        int e0 = ei[pc * (L - 1) + 0];
        const uint4* s4 = (const uint4*)(xb + (size_t)n1 * HD);
        *(uint4*)&Al[0][pl * 200 + gq * 16] = s4[2 * gq];
        *(uint4*)&Al[0][pl * 200 + gq * 16 + 8] = s4[2 * gq + 1];
        const uint4* e4 = (const uint4*)(eab + (size_t)e0 * HD);
        *(uint4*)&Al[0][pl * 200 + 64 + gq * 16] = e4[2 * gq];
        *(uint4*)&Al[0][pl * 200 + 64 + gq * 16 + 8] = e4[2 * gq + 1];
        const uint4* h4 = (const uint4*)(h0b + (size_t)n0 * HD);
        *(uint4*)&Al[0][pl * 200 + 128 + gq * 16] = h4[2 * gq];
        *(uint4*)&Al[0][pl * 200 + 128 + gq * 16 + 8] = h4[2 * gq + 1];
        if (gq == 0) lastnode_s[pl] = paths[pc * L + (L - 1)];
        if (gq == 1) firstnode_s[pl] = n0;
    }
    __syncthreads();

    // ---- initial cell state (issued early, consumed at first activation)
#pragma unroll
    for (int mt = 0; mt < 4; ++mt)
#pragma unroll
        for (int r = 0; r < 4; ++r)
            creg[mt * 4 + r] =
                c0[(size_t)firstnode_s[mt * 16 + q * 4 + r] * HD + 16 * w + c];

#define LOADB(BUF, KC)                                                         \
        { _Pragma("unroll")                                                    \
          for (int g2 = 0; g2 < 4; ++g2)                                       \
              BUF[g2] = Bv[(KC) * 1024 + g2 * 64 + bbase]; }

#define CHUNKS(BUF, KC)                                                        \
        { _Pragma("unroll")                                                    \
          for (int mt = 0; mt < 4; ++mt) {                                     \
              short8v af = *(const short8v*)&Ac[(mt * 16 + c) * 200 + (KC) * 32 + q * 8]; \
              _Pragma("unroll")                                                \
              for (int g2 = 0; g2 < 4; ++g2)                                   \
                  acc[mt][g2] = __builtin_amdgcn_mfma_f32_16x16x32_bf16(       \
                      af, BUF[g2], acc[mt][g2], 0, 0, 0);                      \
          } }

    int cur = 0;
    for (int step = 1; step < L; ++step) {
        const unsigned short* Ac = Al[cur];
        unsigned short* An = Al[cur ^ 1];

#pragma unroll
        for (int mt = 0; mt < 4; ++mt)
#pragma unroll
            for (int g2 = 0; g2 < 4; ++g2) {
                f32x4 v; v[0] = breg[g2]; v[1] = breg[g2]; v[2] = breg[g2]; v[3] = breg[g2];
                acc[mt][g2] = v;
            }

        LOADB(bs0, 0) LOADB(bs1, 1) LOADB(bs2, 2)
        CHUNKS(bs0, 0) LOADB(bs0, 3)
        CHUNKS(bs1, 1) LOADB(bs1, 4)
        CHUNKS(bs2, 2) LOADB(bs2, 5)
        if (step + 1 < L) {   // issue next-step gathers mid-MFMA
            int node = paths[pc * L + step + 1];
            const uint4* s4 = (const uint4*)(xb + (size_t)node * HD);
            nu0 = s4[2 * gq]; nu1 = s4[2 * gq + 1];
            int e = ei[pc * (L - 1) + step];
            const uint4* e4 = (const uint4*)(eab + (size_t)e * HD);
            ev0 = e4[2 * gq]; ev1 = e4[2 * gq + 1];
        }
        CHUNKS(bs0, 3)
        CHUNKS(bs1, 4)
        CHUNKS(bs2, 5)

#pragma unroll
        for (int mt = 0; mt < 4; ++mt) {
#pragma unroll
            for (int r = 0; r < 4; ++r) {
                float gi = acc[mt][0][r], gf = acc[mt][1][r];
                float gg = acc[mt][2][r], go = acc[mt][3][r];
                float ea = __builtin_amdgcn_exp2f(-gf);
                float eb = __builtin_amdgcn_exp2f(-gi);
                float ed = __builtin_amdgcn_exp2f(-gg);
                float eo = __builtin_amdgcn_exp2f(-go);
                float pa = 1.f + ea, pb = 1.f + eb, pd = 1.f + ed;
                float cn = (creg[mt * 4 + r] * pb * pd + (1.f - ed) * pa) *
                           __builtin_amdgcn_rcpf(pa * pb * pd);
                creg[mt * 4 + r] = cn;
                float et = __builtin_amdgcn_exp2f(-2.8853900817779268f * cn);
                float hn = (1.f - et) *
                           __builtin_amdgcn_rcpf((1.f + eo) * (1.f + et));
                if (step < L - 1) {
                    An[(mt * 16 + q * 4 + r) * 200 + 128 + 16 * w + c] = bf16r(hn);
                } else {
                    long pr = (long)blockIdx.x * 64 + mt * 16 + q * 4 + r;
                    if (pr < P) {
                        int node = lastnode_s[mt * 16 + q * 4 + r];
                        atomicAdd(hsum + (size_t)node * HD + 16 * w + c, hn);
                    }
                }
            }
        }

        if (step + 1 < L) {
            *(uint4*)&An[pl * 200 + gq * 16] = nu0;
            *(uint4*)&An[pl * 200 + gq * 16 + 8] = nu1;
            *(uint4*)&An[pl * 200 + 64 + gq * 16] = ev0;
            *(uint4*)&An[pl * 200 + 64 + gq * 16 + 8] = ev1;
            __syncthreads();
        }
        cur ^= 1;
    }
#undef LOADB
#undef CHUNKS
}

// ---------------------------------------------------------------------------
// Per-column sum / sumsq over rows (for BN stats)
// ---------------------------------------------------------------------------
__global__ void col_stats(const float* __restrict__ X, int nrows, float* __restrict__ out) {
    int col = threadIdx.x & 63, rg = threadIdx.x >> 6;
    float s = 0.f, q = 0.f;
    long stride = (long)gridDim.x * 4;
    for (long r = (long)blockIdx.x * 4 + rg; r < nrows; r += stride) {
        float v = X[r * 64 + col];
        s += v;
        q += v * v;
    }
    __shared__ float red[2][256];
    red[0][threadIdx.x] = s;
    red[1][threadIdx.x] = q;
    __syncthreads();
    if (threadIdx.x < 64) {
        int c = threadIdx.x;
        float ss = red[0][c] + red[0][c + 64] + red[0][c + 128] + red[0][c + 192];
        float qq = red[1][c] + red[1][c + 64] + red[1][c + 128] + red[1][c + 192];
        atomicAdd(out + c, ss);
        atomicAdd(out + 64 + c, qq);
    }
}

// per-thread BN affine from raw stats
__device__ __forceinline__ void bn_affine(const float* stats, const float* g,
                                          const float* b, int col, int nrows,
                                          float& a, float& c) {
    float inv = 1.0f / (float)nrows;
    float mean = stats[col] * inv;
    float var = stats[64 + col] * inv - mean * mean;
    a = g[col] * rsqrtf(var + 1e-5f);
    c = b[col] - mean * a;
}

// ---------------------------------------------------------------------------
// Y[n][j] = sum_k inAct(X[n][k]*a[k]+c[k]) * W[k][j] + bias[j]
// ---------------------------------------------------------------------------
template <bool INRELU, bool STATS>
__global__ __launch_bounds__(256)
void gemm64(const float* __restrict__ X, const float* __restrict__ stats_in,
            const float* __restrict__ bn_gm, const float* __restrict__ bn_bt,
            const float* __restrict__ W, const float* __restrict__ bias,
            float* __restrict__ Y, float* stats, int nrows) {
    __shared__ float Xs[64 * 64];
    __shared__ float red[2][256];
    const int t = threadIdx.x;
    const int col = t & 63, rg = t >> 6;
    const long r0 = (long)blockIdx.x * 64;

    float a = 1.f, c = 0.f;
    if (stats_in) bn_affine(stats_in, bn_gm, bn_bt, col, nrows, a, c);

    for (int i = 0; i < 16; ++i) {
        int rl = rg * 16 + i;
        long r = r0 + rl;
        float v = (r < nrows) ? X[r * 64 + col] : 0.f;
        v = v * a + c;
        if (INRELU) v = fmaxf(v, 0.f);
        Xs[rl * 64 + col] = v;
    }
    __syncthreads();

    float wreg[64];
#pragma unroll
    for (int k = 0; k < 64; ++k) wreg[k] = W[k * 64 + col];
    float bs = bias[col];
    float ssum = 0.f, ssq = 0.f;

    for (int i = 0; i < 16; ++i) {
        int rl = rg * 16 + i;
        long r = r0 + rl;
        const float4* xs4 = (const float4*)(Xs + rl * 64);
        float acc = bs;
#pragma unroll
        for (int k4 = 0; k4 < 16; ++k4) {
            float4 xv = xs4[k4];
            acc += xv.x * wreg[4 * k4] + xv.y * wreg[4 * k4 + 1] +
                   xv.z * wreg[4 * k4 + 2] + xv.w * wreg[4 * k4 + 3];
        }
        if (r < nrows) {
            Y[r * 64 + col] = acc;
            ssum += acc;
            ssq += acc * acc;
        }
    }
    if (STATS) {
        red[0][t] = ssum;
        red[1][t] = ssq;
        __syncthreads();
        if (t < 64) {
            float s = red[0][t] + red[0][t + 64] + red[0][t + 128] + red[0][t + 192];
            float qq = red[1][t] + red[1][t + 64] + red[1][t + 128] + red[1][t + 192];
            atomicAdd(stats + t, s);
            atomicAdd(stats + 64 + t, qq);
        }
    }
}

// conv1 epilogue: W1 = relu(BN(W1)); Winb = bf16(0.75*W0 - 0.25*W1)
__global__ void bn_apply1(float* __restrict__ W1, const float* __restrict__ stats,
                          const float* __restrict__ g, const float* __restrict__ b,
                          const float* __restrict__ W0, unsigned short* __restrict__ Winb,
                          long n) {
    long gid = (long)blockIdx.x * 256 + threadIdx.x;
    if (gid >= n * 64) return;
    int col = (int)(gid & 63);
    float a, c;
    bn_affine(stats, g, b, col, (int)n, a, c);
    float v = fmaxf(W1[gid] * a + c, 0.f);
    W1[gid] = v;
    Winb[gid] = bf16r(0.75f * W0[gid] - 0.25f * v);
}

// conv2 epilogue fused with attention dots
__global__ void bn_apply_att(float* __restrict__ W2, const float* __restrict__ stats,
                             const float* __restrict__ g, const float* __restrict__ b,
                             const float* __restrict__ W0, const float* __restrict__ W1,
                             float* __restrict__ atts, int n) {
    int col = threadIdx.x & 63, rg = threadIdx.x >> 6;
    float a, c;
    bn_affine(stats, g, b, col, n, a, c);
    float s1 = 0.f, s2 = 0.f;
    long stride = (long)gridDim.x * 4;
    for (long r = (long)blockIdx.x * 4 + rg; r < n; r += stride) {
        long gid = r * 64 + col;
        float v = fmaxf(W2[gid] * a + c, 0.f);
        W2[gid] = v;
        float q0 = W0[gid];
        s1 += q0 * W1[gid];
        s2 += q0 * v;
    }
    __shared__ float red[2][256];
    red[0][threadIdx.x] = s1;
    red[1][threadIdx.x] = s2;
    __syncthreads();
    if (threadIdx.x < 64) {
        int cc = threadIdx.x;
        float a1 = red[0][cc] + red[0][cc + 64] + red[0][cc + 128] + red[0][cc + 192];
        float a2 = red[1][cc] + red[1][cc + 64] + red[1][cc + 128] + red[1][cc + 192];
        atomicAdd(atts + cc, a1);
        atomicAdd(atts + 64 + cc, a2);
    }
}

// rep pooling with per-block softmax recompute
#define PROWS 128
__global__ void pool_rep(const float* __restrict__ W0, const float* __restrict__ W1,
                         const float* __restrict__ W2, const float* __restrict__ atts,
                         const float* __restrict__ w_att, const float* __restrict__ b_att,
                         const int* __restrict__ batch, float* __restrict__ pooled, int n) {
    __shared__ float wsh[2];
    if (threadIdx.x < 64) {
        int h = threadIdx.x;
        float z[2];
        for (int k = 0; k < 2; ++k) {
            float s = atts[64 * k + h];
            float mn = s, mx = s;
            for (int off = 32; off > 0; off >>= 1) {
                mn = fminf(mn, __shfl_down(mn, off));
                mx = fmaxf(mx, __shfl_down(mx, off));
            }
            mn = __shfl(mn, 0);
            mx = __shfl(mx, 0);
            float sn = (s - mn) / (mx - mn + 1e-6f);
            float d = sn * w_att[h];
            for (int off = 32; off > 0; off >>= 1) d += __shfl_down(d, off);
            z[k] = __shfl(d, 0) + b_att[0];
        }
        if (h == 0) {
            float m = fmaxf(z[0], z[1]);
            float e0 = expf(z[0] - m), e1 = expf(z[1] - m);
            float inv = 1.0f / (e0 + e1);
            wsh[0] = e0 * inv;
            wsh[1] = e1 * inv;
        }
    }
    __syncthreads();
    int col = threadIdx.x & 63, rg = threadIdx.x >> 6;
    long r0 = (long)blockIdx.x * PROWS;
    float w1 = wsh[0], w2 = wsh[1];
    float acc = 0.f;
    int curg = -1;
    for (int i = rg; i < PROWS; i += 4) {
        long r = r0 + i;
        if (r >= n) break;
        int g = batch[r];
        long gid = r * 64 + col;
        float rep = W0[gid] + w1 * W1[gid] + w2 * W2[gid];
        if (g != curg) {
            if (curg >= 0) atomicAdd(pooled + (size_t)curg * 64 + col, acc);
            curg = g;
            acc = 0.f;
        }
        acc += rep;
    }
    if (curg >= 0) atomicAdd(pooled + (size_t)curg * 64 + col, acc);
}

// fused head
__global__ __launch_bounds__(256)
void head_kernel(const float* __restrict__ pooled, const float* __restrict__ w_l1,
                 const float* __restrict__ b_l1, const float* __restrict__ w_l2,
                 const float* __restrict__ b_l2, float* __restrict__ out) {
    __shared__ float Xs[64 * 64];
    __shared__ float Ys[64 * 65];
    const int t = threadIdx.x;
    const int col = t & 63, rg = t >> 6;
    const int r0 = blockIdx.x * 64;

    for (int i = 0; i < 16; ++i) {
        int rl = rg * 16 + i;
        Xs[rl * 64 + col] = fmaxf(pooled[(size_t)(r0 + rl) * 64 + col], 0.f);
    }
    __syncthreads();

    float wreg[64];
#pragma unroll
    for (int k = 0; k < 64; ++k) wreg[k] = w_l1[k * 64 + col];
    float bs = b_l1[col];

    for (int i = 0; i < 16; ++i) {
        int rl = rg * 16 + i;
        const float4* xs4 = (const float4*)(Xs + rl * 64);
        float acc = bs;
#pragma unroll
        for (int k4 = 0; k4 < 16; ++k4) {
            float4 xv = xs4[k4];
            acc += xv.x * wreg[4 * k4] + xv.y * wreg[4 * k4 + 1] +
                   xv.z * wreg[4 * k4 + 2] + xv.w * wreg[4 * k4 + 3];
        }
        Ys[rl * 65 + col] = fmaxf(acc, 0.f);
    }
    __syncthreads();

    for (int idx = t; idx < 64 * NCLS; idx += 256) {
        int row = idx / NCLS, j = idx - row * NCLS;
        float acc = b_l2[j];
#pragma unroll
        for (int k = 0; k < 64; ++k) acc += Ys[row * 65 + k] * w_l2[k * NCLS + j];
        out[(size_t)(r0 + row) * NCLS + j] = acc;
    }
}

// ---------------------------------------------------------------------------
extern "C" void kernel_launch(void* const* d_in, const int* in_sizes, int n_in,
                              void* d_out, int out_size, void* d_ws, size_t ws_size,
                              hipStream_t stream) {
    const float* x         = (const float*)d_in[0];
    const float* edge_attr = (const float*)d_in[1];
    const int*   paths2    = (const int*)d_in[2];
    const int*   ei2       = (const int*)d_in[3];
    const int*   paths3    = (const int*)d_in[4];
    const int*   ei3       = (const int*)d_in[5];
    const int*   batch     = (const int*)d_in[6];
    const float* w_feat    = (const float*)d_in[7];
    const float* b_feat    = (const float*)d_in[8];
    const float* w_bond    = (const float*)d_in[9];
    const float* b_bond    = (const float*)d_in[10];
    const float* w_ih      = (const float*)d_in[11];
    const float* w_hh      = (const float*)d_in[12];
    const float* b_ih      = (const float*)d_in[13];
    const float* b_hh      = (const float*)d_in[14];
    const float* bn_g      = (const float*)d_in[15];
    const float* bn_b      = (const float*)d_in[16];
    const float* mlp_w1    = (const float*)d_in[17];
    const float* mlp_b1    = (const float*)d_in[18];
    const float* bn1_g     = (const float*)d_in[19];
    const float* bn1_b     = (const float*)d_in[20];
    const float* mlp_w2    = (const float*)d_in[21];
    const float* mlp_b2    = (const float*)d_in[22];
    const float* bn2_g     = (const float*)d_in[23];
    const float* bn2_b     = (const float*)d_in[24];
    const float* w_att     = (const float*)d_in[25];
    const float* b_att     = (const float*)d_in[26];
    const float* w_l1      = (const float*)d_in[27];
    const float* b_l1      = (const float*)d_in[28];
    const float* w_l2      = (const float*)d_in[29];
    const float* b_l2      = (const float*)d_in[30];

    const size_t N64 = (size_t)NNODES * 64;
    float* ws = (float*)d_ws;
    float* W0     = ws;
    float* W1     = W0 + N64;
    float* W2     = W1 + N64;     // also aliased as c0 until chain-2 gemm2 (lifetimes disjoint)
    float* Wtmp   = W2 + N64;
    float* hsum1  = Wtmp + N64;
    float* hsum2  = hsum1 + N64;
    unsigned short* W0b  = (unsigned short*)(hsum2 + N64);
    unsigned short* Winb = W0b + N64;
    unsigned short* eab  = Winb + N64;
    unsigned short* Bp   = eab + (size_t)NEDGES * 64;
    float* bsum   = (float*)(Bp + 6 * 16 * 64 * 8);
    float* st     = bsum + 256;
    float* atts   = st + 6 * 128;
    float* watt   = atts + 128;
    float* pooled = watt + 64;
    unsigned short* h0b = (unsigned short*)(pooled + (size_t)NG * 64);  // N*64 bf16
    float* c0 = W2;   // f32 initial cell state; dead before W2 is first written
    float* outp   = (float*)d_out;

    // single fused prep: encode + Bp + bsum + zero(st/atts/watt, hsum1+hsum2, pooled)
    prep_encode<<<NB_ENC + 193 + 3200 + 512, 256, 0, stream>>>(
        x, w_feat, b_feat, edge_attr, w_bond, b_bond, W0, W0b, eab,
        w_ih, w_hh, b_ih, b_hh, Bp, bsum, st, hsum1, pooled);

    // ---------------- conv 1 (L=2, single full step) ----------------
    // step-0 state from conv1's input encoding (W0b)
    init_state<<<(NNODES + 63) / 64, 256, 0, stream>>>(W0b, Bp, bsum, h0b, c0);
    conv_mfma<2><<<(NP2 + 63) / 64, 256, 0, stream>>>(W0b, eab, h0b, c0, paths2, ei2, Bp, bsum, hsum1, NP2);

    col_stats<<<1024, 256, 0, stream>>>(hsum1, NNODES, st + 0);
    gemm64<false, true><<<(NNODES + 63) / 64, 256, 0, stream>>>(hsum1, st + 0, bn_g + 0, bn_b + 0, mlp_w1, mlp_b1, Wtmp, st + 128, NNODES);
    gemm64<true, true><<<(NNODES + 63) / 64, 256, 0, stream>>>(Wtmp, st + 128, bn1_g + 0, bn1_b + 0, mlp_w2, mlp_b2, W1, st + 256, NNODES);
    bn_apply1<<<(int)((N64 + 255) / 256), 256, 0, stream>>>(W1, st + 256, bn2_g + 0, bn2_b + 0, W0, Winb, NNODES);

    // ---------------- conv 2 (L=3, two full steps) ----------------
    // step-0 state recomputed from conv2's input encoding (Winb) — R9's bug
    init_state<<<(NNODES + 63) / 64, 256, 0, stream>>>(Winb, Bp, bsum, h0b, c0);
    conv_mfma<3><<<(NP3 + 63) / 64, 256, 0, stream>>>(Winb, eab, h0b, c0, paths3, ei3, Bp, bsum, hsum2, NP3);

    col_stats<<<1024, 256, 0, stream>>>(hsum2, NNODES, st + 384);
    gemm64<false, true><<<(NNODES + 63) / 64, 256, 0, stream>>>(hsum2, st + 384, bn_g + 64, bn_b + 64, mlp_w1 + 4096, mlp_b1 + 64, Wtmp, st + 512, NNODES);
    gemm64<true, true><<<(NNODES + 63) / 64, 256, 0, stream>>>(Wtmp, st + 512, bn1_g + 64, bn1_b + 64, mlp_w2 + 4096, mlp_b2 + 64, W2, st + 640, NNODES);
    bn_apply_att<<<1024, 256, 0, stream>>>(W2, st + 640, bn2_g + 64, bn2_b + 64, W0, W1, atts, NNODES);

    // ---------------- attention + pooling + head ----------------
    pool_rep<<<(NNODES + PROWS - 1) / PROWS, 256, 0, stream>>>(W0, W1, W2, atts, w_att, b_att, batch, pooled, NNODES);
    head_kernel<<<NG / 64, 256, 0, stream>>>(pooled, w_l1, b_l1, w_l2, b_l2, outp);
}

// Round 11
// 711.251 us; speedup vs baseline: 1.1269x; 1.1269x over previous
//
#include <hip/hip_runtime.h>
#include <math.h>

#define NNODES 100000
#define NEDGES 200000
#define HD 64
#define NP2 250000
#define NP3 500000
#define NG 2048
#define NCLS 10
#define NFEAT 18
#define EFEAT 18

typedef short short8v __attribute__((ext_vector_type(8)));
typedef float f32x4 __attribute__((ext_vector_type(4)));

__device__ __forceinline__ unsigned short bf16r(float a) {
    unsigned u = __builtin_bit_cast(unsigned, a);
    return (unsigned short)((u + 0x7FFFu + ((u >> 16) & 1u)) >> 16);
}

#define LOG2E 1.4426950408889634f

// ---------------------------------------------------------------------------
// Fused prep + encode + zeroing (one dispatch).
// ---------------------------------------------------------------------------
#define NB_ENC (((NNODES + NEDGES) * 64 + 255) / 256)

__global__ void prep_encode(const float* __restrict__ X, const float* __restrict__ Wf,
                            const float* __restrict__ bf,
                            const float* __restrict__ Ea, const float* __restrict__ Wb,
                            const float* __restrict__ bb,
                            float* __restrict__ W0, unsigned short* __restrict__ W0b,
                            unsigned short* __restrict__ eab,
                            const float* __restrict__ w_ih, const float* __restrict__ w_hh,
                            const float* __restrict__ b_ih, const float* __restrict__ b_hh,
                            unsigned short* __restrict__ Bp, float* __restrict__ bsum,
                            float* __restrict__ zsmall, float* __restrict__ hzero,
                            float* __restrict__ pooled) {
    int b = blockIdx.x;
    int t = threadIdx.x;
    if (b < NB_ENC) {
        long gid = (long)b * 256 + t;
        if (gid >= (long)(NNODES + NEDGES) * 64) return;
        long r = gid >> 6;
        int col = (int)(gid & 63);
        if (r < NNODES) {
            float acc = bf[col];
            const float* xr = X + r * NFEAT;
            for (int k = 0; k < NFEAT; ++k) acc += xr[k] * Wf[k * 64 + col];
            W0[gid] = acc;
            W0b[gid] = bf16r(acc);
        } else {
            long r2 = r - NNODES;
            float acc = bb[col];
            const float* xr = Ea + r2 * EFEAT;
            for (int k = 0; k < EFEAT; ++k) acc += xr[k] * Wb[k * 64 + col];
            eab[r2 * 64 + col] = bf16r(acc);
        }
    } else if (b < NB_ENC + 192) {
        int gid = (b - NB_ENC) * 256 + t;
        int kc = gid >> 13;
        int rem = gid & 8191;
        int nt = rem >> 9;
        int rem2 = rem & 511;
        int l = rem2 >> 3, j = rem2 & 7;
        int c = l & 15, q = l >> 4;
        int jh = nt >> 2, qg = nt & 3;
        int k = kc * 32 + q * 8 + j;
        int n = qg * 64 + 16 * jh + c;
        float f = (k < 128) ? w_ih[n * 128 + k] : w_hh[n * 64 + (k - 128)];
        float s = (qg == 2) ? 2.f * LOG2E : LOG2E;
        Bp[gid] = bf16r(f * s);
    } else if (b == NB_ENC + 192) {
        float s = ((t >> 6) == 2) ? 2.f * LOG2E : LOG2E;
        bsum[t] = (b_ih[t] + b_hh[t]) * s;
        for (int i = t; i < 960; i += 256) zsmall[i] = 0.f;
    } else if (b < NB_ENC + 193 + 3200) {
        long base = ((long)(b - NB_ENC - 193) * 256 + t) * 16;
        f32x4 z = {0.f, 0.f, 0.f, 0.f};
        f32x4* p = (f32x4*)(hzero + base);
        long lim = 2L * NNODES * 64;
        if (base + 16 <= lim) { p[0] = z; p[1] = z; p[2] = z; p[3] = z; }
    } else {
        pooled[(b - NB_ENC - 193 - 3200) * 256 + t] = 0.f;
    }
}

// ---------------------------------------------------------------------------
// MFMA LSTM path conv — EXACT R4/R8 code (twice-verified best: ~186 µs
// conv<3>, FETCH 144 MB, WRITE 138 MB, VALUBusy 56%).  Streamed B via
// 3-slot rotation, mid-MFMA gathers, lastnode staging, double-buffered LDS,
// 1 barrier/step, 3 blk/CU.
// DO NOT TOUCH:
//  - persistent-chunk0/bias-C variants regressed 3x (R2/R3/R6)
//  - 2-slot rotation / post-MFMA gathers regressed (R2)
//  - single-buffer 4 blk/CU regressed (R5: L2 thrash)
//  - step-0 hoist to per-node state regressed (R10: +162 MB gather traffic
//    > recomputation cost; state-gather bytes dominate on latency-bound conv)
// ---------------------------------------------------------------------------
template <int L>
__global__ __launch_bounds__(256, 3)
void conv_mfma(const unsigned short* __restrict__ xb, const unsigned short* __restrict__ eab,
               const int* __restrict__ paths, const int* __restrict__ ei,
               const unsigned short* __restrict__ Bp, const float* __restrict__ bsum,
               float* __restrict__ hsum, int P) {
    __shared__ unsigned short Al[2][64 * 200];
    __shared__ int lastnode_s[64];

    const int t = threadIdx.x;
    const int w = t >> 6, lane = t & 63;
    const int c = lane & 15, q = lane >> 4;
    const int pl = t >> 2, gq = t & 3;
    const long pg = (long)blockIdx.x * 64 + pl;
    const int pc = (pg < P) ? (int)pg : P - 1;

    const short8v* __restrict__ Bv = (const short8v*)Bp;
    const int bbase = w * 256 + lane;

    float breg[4];
#pragma unroll
    for (int g2 = 0; g2 < 4; ++g2) breg[g2] = bsum[g2 * 64 + 16 * w + c];

    float creg[16];
#pragma unroll
    for (int i = 0; i < 16; ++i) creg[i] = 0.f;

    f32x4 acc[4][4];
    short8v bs0[4], bs1[4], bs2[4];
    uint4 nu0, nu1, ev0, ev1;

    {
        int node = paths[pc * L + 0];
        const uint4* s4 = (const uint4*)(xb + (size_t)node * HD);
        *(uint4*)&Al[0][pl * 200 + gq * 16] = s4[2 * gq];
        *(uint4*)&Al[0][pl * 200 + gq * 16 + 8] = s4[2 * gq + 1];
        if (gq == 0) lastnode_s[pl] = paths[pc * L + (L - 1)];
    }
    __syncthreads();

#define LOADB(BUF, KC)                                                         \
        { _Pragma("unroll")                                                    \
          for (int g2 = 0; g2 < 4; ++g2)                                       \
              BUF[g2] = Bv[(KC) * 1024 + g2 * 64 + bbase]; }

#define CHUNKS(BUF, KC)                                                        \
        { _Pragma("unroll")                                                    \
          for (int mt = 0; mt < 4; ++mt) {                                     \
              short8v af = *(const short8v*)&Ac[(mt * 16 + c) * 200 + (KC) * 32 + q * 8]; \
              _Pragma("unroll")                                                \
              for (int g2 = 0; g2 < 4; ++g2)                                   \
                  acc[mt][g2] = __builtin_amdgcn_mfma_f32_16x16x32_bf16(       \
                      af, BUF[g2], acc[mt][g2], 0, 0, 0);                      \
          } }

    int cur = 0;
    for (int step = 0; step < L; ++step) {
        const unsigned short* Ac = Al[cur];
        unsigned short* An = Al[cur ^ 1];

#pragma unroll
        for (int mt = 0; mt < 4; ++mt)
#pragma unroll
            for (int g2 = 0; g2 < 4; ++g2) {
                f32x4 v; v[0] = breg[g2]; v[1] = breg[g2]; v[2] = breg[g2]; v[3] = breg[g2];
                acc[mt][g2] = v;
            }

        if (step == 0) {
            LOADB(bs0, 0)
            LOADB(bs1, 1)
            {
                int node = paths[pc * L + 1];
                const uint4* s4 = (const uint4*)(xb + (size_t)node * HD);
                nu0 = s4[2 * gq]; nu1 = s4[2 * gq + 1];
                int e = ei[pc * (L - 1) + 0];
                const uint4* e4 = (const uint4*)(eab + (size_t)e * HD);
                ev0 = e4[2 * gq]; ev1 = e4[2 * gq + 1];
            }
            CHUNKS(bs0, 0)
            CHUNKS(bs1, 1)
        } else {
            LOADB(bs0, 0) LOADB(bs1, 1) LOADB(bs2, 2)
            CHUNKS(bs0, 0) LOADB(bs0, 3)
            CHUNKS(bs1, 1) LOADB(bs1, 4)
            CHUNKS(bs2, 2) LOADB(bs2, 5)
            if (step + 1 < L) {
                int node = paths[pc * L + step + 1];
                const uint4* s4 = (const uint4*)(xb + (size_t)node * HD);
                nu0 = s4[2 * gq]; nu1 = s4[2 * gq + 1];
                int e = ei[pc * (L - 1) + step];
                const uint4* e4 = (const uint4*)(eab + (size_t)e * HD);
                ev0 = e4[2 * gq]; ev1 = e4[2 * gq + 1];
            }
            CHUNKS(bs0, 3)
            CHUNKS(bs1, 4)
            CHUNKS(bs2, 5)
        }

#pragma unroll
        for (int mt = 0; mt < 4; ++mt) {
#pragma unroll
            for (int r = 0; r < 4; ++r) {
                float gi = acc[mt][0][r], gf = acc[mt][1][r];
                float gg = acc[mt][2][r], go = acc[mt][3][r];
                float ea = __builtin_amdgcn_exp2f(-gf);
                float eb = __builtin_amdgcn_exp2f(-gi);
                float ed = __builtin_amdgcn_exp2f(-gg);
                float eo = __builtin_amdgcn_exp2f(-go);
                float pa = 1.f + ea, pb = 1.f + eb, pd = 1.f + ed;
                float cn = (creg[mt * 4 + r] * pb * pd + (1.f - ed) * pa) *
                           __builtin_amdgcn_rcpf(pa * pb * pd);
                creg[mt * 4 + r] = cn;
                float et = __builtin_amdgcn_exp2f(-2.8853900817779268f * cn);
                float hn = (1.f - et) *
                           __builtin_amdgcn_rcpf((1.f + eo) * (1.f + et));
                if (step < L - 1) {
                    Al[cur ^ 1][(mt * 16 + q * 4 + r) * 200 + 128 + 16 * w + c] = bf16r(hn);
                } else {
                    long pr = (long)blockIdx.x * 64 + mt * 16 + q * 4 + r;
                    if (pr < P) {
                        int node = lastnode_s[mt * 16 + q * 4 + r];
                        atomicAdd(hsum + (size_t)node * HD + 16 * w + c, hn);
                    }
                }
            }
        }

        if (step + 1 < L) {
            *(uint4*)&An[pl * 200 + gq * 16] = nu0;
            *(uint4*)&An[pl * 200 + gq * 16 + 8] = nu1;
            *(uint4*)&An[pl * 200 + 64 + gq * 16] = ev0;
            *(uint4*)&An[pl * 200 + 64 + gq * 16 + 8] = ev1;
            __syncthreads();
        }
        cur ^= 1;
    }
#undef LOADB
#undef CHUNKS
}

// ---------------------------------------------------------------------------
// Per-column sum / sumsq over rows (for BN stats)
// ---------------------------------------------------------------------------
__global__ void col_stats(const float* __restrict__ X, int nrows, float* __restrict__ out) {
    int col = threadIdx.x & 63, rg = threadIdx.x >> 6;
    float s = 0.f, q = 0.f;
    long stride = (long)gridDim.x * 4;
    for (long r = (long)blockIdx.x * 4 + rg; r < nrows; r += stride) {
        float v = X[r * 64 + col];
        s += v;
        q += v * v;
    }
    __shared__ float red[2][256];
    red[0][threadIdx.x] = s;
    red[1][threadIdx.x] = q;
    __syncthreads();
    if (threadIdx.x < 64) {
        int c = threadIdx.x;
        float ss = red[0][c] + red[0][c + 64] + red[0][c + 128] + red[0][c + 192];
        float qq = red[1][c] + red[1][c + 64] + red[1][c + 128] + red[1][c + 192];
        atomicAdd(out + c, ss);
        atomicAdd(out + 64 + c, qq);
    }
}

// per-thread BN affine from raw stats
__device__ __forceinline__ void bn_affine(const float* stats, const float* g,
                                          const float* b, int col, int nrows,
                                          float& a, float& c) {
    float inv = 1.0f / (float)nrows;
    float mean = stats[col] * inv;
    float var = stats[64 + col] * inv - mean * mean;
    a = g[col] * rsqrtf(var + 1e-5f);
    c = b[col] - mean * a;
}

// ---------------------------------------------------------------------------
// Y[n][j] = sum_k inAct(X[n][k]*a[k]+c[k]) * W[k][j] + bias[j]
// ---------------------------------------------------------------------------
template <bool INRELU, bool STATS>
__global__ __launch_bounds__(256)
void gemm64(const float* __restrict__ X, const float* __restrict__ stats_in,
            const float* __restrict__ bn_gm, const float* __restrict__ bn_bt,
            const float* __restrict__ W, const float* __restrict__ bias,
            float* __restrict__ Y, float* stats, int nrows) {
    __shared__ float Xs[64 * 64];
    __shared__ float red[2][256];
    const int t = threadIdx.x;
    const int col = t & 63, rg = t >> 6;
    const long r0 = (long)blockIdx.x * 64;

    float a = 1.f, c = 0.f;
    if (stats_in) bn_affine(stats_in, bn_gm, bn_bt, col, nrows, a, c);

    for (int i = 0; i < 16; ++i) {
        int rl = rg * 16 + i;
        long r = r0 + rl;
        float v = (r < nrows) ? X[r * 64 + col] : 0.f;
        v = v * a + c;
        if (INRELU) v = fmaxf(v, 0.f);
        Xs[rl * 64 + col] = v;
    }
    __syncthreads();

    float wreg[64];
#pragma unroll
    for (int k = 0; k < 64; ++k) wreg[k] = W[k * 64 + col];
    float bs = bias[col];
    float ssum = 0.f, ssq = 0.f;

    for (int i = 0; i < 16; ++i) {
        int rl = rg * 16 + i;
        long r = r0 + rl;
        const float4* xs4 = (const float4*)(Xs + rl * 64);
        float acc = bs;
#pragma unroll
        for (int k4 = 0; k4 < 16; ++k4) {
            float4 xv = xs4[k4];
            acc += xv.x * wreg[4 * k4] + xv.y * wreg[4 * k4 + 1] +
                   xv.z * wreg[4 * k4 + 2] + xv.w * wreg[4 * k4 + 3];
        }
        if (r < nrows) {
            Y[r * 64 + col] = acc;
            ssum += acc;
            ssq += acc * acc;
        }
    }
    if (STATS) {
        red[0][t] = ssum;
        red[1][t] = ssq;
        __syncthreads();
        if (t < 64) {
            float s = red[0][t] + red[0][t + 64] + red[0][t + 128] + red[0][t + 192];
            float qq = red[1][t] + red[1][t + 64] + red[1][t + 128] + red[1][t + 192];
            atomicAdd(stats + t, s);
            atomicAdd(stats + 64 + t, qq);
        }
    }
}

// conv1 epilogue: W1 = relu(BN(W1)); Winb = bf16(0.75*W0 - 0.25*W1)
// float4/ushort4-vectorized (G13); per-element math identical to scalar.
__global__ void bn_apply1(float* __restrict__ W1, const float* __restrict__ stats,
                          const float* __restrict__ g, const float* __restrict__ b,
                          const float* __restrict__ W0, unsigned short* __restrict__ Winb,
                          long n) {
    long gid = ((long)blockIdx.x * 256 + threadIdx.x) * 4;
    if (gid >= n * 64) return;
    int col = (int)(gid & 63);
    float inv = 1.0f / (float)n;
    float4 sm = *(const float4*)(stats + col);
    float4 sq = *(const float4*)(stats + 64 + col);
    float4 gm = *(const float4*)(g + col);
    float4 bt = *(const float4*)(b + col);
    float m0 = sm.x * inv, m1 = sm.y * inv, m2 = sm.z * inv, m3 = sm.w * inv;
    float a0 = gm.x * rsqrtf(sq.x * inv - m0 * m0 + 1e-5f);
    float a1 = gm.y * rsqrtf(sq.y * inv - m1 * m1 + 1e-5f);
    float a2 = gm.z * rsqrtf(sq.z * inv - m2 * m2 + 1e-5f);
    float a3 = gm.w * rsqrtf(sq.w * inv - m3 * m3 + 1e-5f);
    float c0 = bt.x - m0 * a0, c1 = bt.y - m1 * a1;
    float c2 = bt.z - m2 * a2, c3 = bt.w - m3 * a3;
    float4 w1 = *(const float4*)(W1 + gid);
    float4 w0 = *(const float4*)(W0 + gid);
    float r0 = fmaxf(w1.x * a0 + c0, 0.f);
    float r1 = fmaxf(w1.y * a1 + c1, 0.f);
    float r2 = fmaxf(w1.z * a2 + c2, 0.f);
    float r3 = fmaxf(w1.w * a3 + c3, 0.f);
    float4 rv; rv.x = r0; rv.y = r1; rv.z = r2; rv.w = r3;
    *(float4*)(W1 + gid) = rv;
    ushort4 ob;
    ob.x = bf16r(0.75f * w0.x - 0.25f * r0);
    ob.y = bf16r(0.75f * w0.y - 0.25f * r1);
    ob.z = bf16r(0.75f * w0.z - 0.25f * r2);
    ob.w = bf16r(0.75f * w0.w - 0.25f * r3);
    *(ushort4*)(Winb + gid) = ob;
}

// conv2 epilogue fused with attention dots
__global__ void bn_apply_att(float* __restrict__ W2, const float* __restrict__ stats,
                             const float* __restrict__ g, const float* __restrict__ b,
                             const float* __restrict__ W0, const float* __restrict__ W1,
                             float* __restrict__ atts, int n) {
    int col = threadIdx.x & 63, rg = threadIdx.x >> 6;
    float a, c;
    bn_affine(stats, g, b, col, n, a, c);
    float s1 = 0.f, s2 = 0.f;
    long stride = (long)gridDim.x * 4;
    for (long r = (long)blockIdx.x * 4 + rg; r < n; r += stride) {
        long gid = r * 64 + col;
        float v = fmaxf(W2[gid] * a + c, 0.f);
        W2[gid] = v;
        float q0 = W0[gid];
        s1 += q0 * W1[gid];
        s2 += q0 * v;
    }
    __shared__ float red[2][256];
    red[0][threadIdx.x] = s1;
    red[1][threadIdx.x] = s2;
    __syncthreads();
    if (threadIdx.x < 64) {
        int cc = threadIdx.x;
        float a1 = red[0][cc] + red[0][cc + 64] + red[0][cc + 128] + red[0][cc + 192];
        float a2 = red[1][cc] + red[1][cc + 64] + red[1][cc + 128] + red[1][cc + 192];
        atomicAdd(atts + cc, a1);
        atomicAdd(atts + 64 + cc, a2);
    }
}

// rep pooling with per-block softmax recompute
#define PROWS 128
__global__ void pool_rep(const float* __restrict__ W0, const float* __restrict__ W1,
                         const float* __restrict__ W2, const float* __restrict__ atts,
                         const float* __restrict__ w_att, const float* __restrict__ b_att,
                         const int* __restrict__ batch, float* __restrict__ pooled, int n) {
    __shared__ float wsh[2];
    if (threadIdx.x < 64) {
        int h = threadIdx.x;
        float z[2];
        for (int k = 0; k < 2; ++k) {
            float s = atts[64 * k + h];
            float mn = s, mx = s;
            for (int off = 32; off > 0; off >>= 1) {
                mn = fminf(mn, __shfl_down(mn, off));
                mx = fmaxf(mx, __shfl_down(mx, off));
            }
            mn = __shfl(mn, 0);
            mx = __shfl(mx, 0);
            float sn = (s - mn) / (mx - mn + 1e-6f);
            float d = sn * w_att[h];
            for (int off = 32; off > 0; off >>= 1) d += __shfl_down(d, off);
            z[k] = __shfl(d, 0) + b_att[0];
        }
        if (h == 0) {
            float m = fmaxf(z[0], z[1]);
            float e0 = expf(z[0] - m), e1 = expf(z[1] - m);
            float inv = 1.0f / (e0 + e1);
            wsh[0] = e0 * inv;
            wsh[1] = e1 * inv;
        }
    }
    __syncthreads();
    int col = threadIdx.x & 63, rg = threadIdx.x >> 6;
    long r0 = (long)blockIdx.x * PROWS;
    float w1 = wsh[0], w2 = wsh[1];
    float acc = 0.f;
    int curg = -1;
    for (int i = rg; i < PROWS; i += 4) {
        long r = r0 + i;
        if (r >= n) break;
        int g = batch[r];
        long gid = r * 64 + col;
        float rep = W0[gid] + w1 * W1[gid] + w2 * W2[gid];
        if (g != curg) {
            if (curg >= 0) atomicAdd(pooled + (size_t)curg * 64 + col, acc);
            curg = g;
            acc = 0.f;
        }
        acc += rep;
    }
    if (curg >= 0) atomicAdd(pooled + (size_t)curg * 64 + col, acc);
}

// fused head
__global__ __launch_bounds__(256)
void head_kernel(const float* __restrict__ pooled, const float* __restrict__ w_l1,
                 const float* __restrict__ b_l1, const float* __restrict__ w_l2,
                 const float* __restrict__ b_l2, float* __restrict__ out) {
    __shared__ float Xs[64 * 64];
    __shared__ float Ys[64 * 65];
    const int t = threadIdx.x;
    const int col = t & 63, rg = t >> 6;
    const int r0 = blockIdx.x * 64;

    for (int i = 0; i < 16; ++i) {
        int rl = rg * 16 + i;
        Xs[rl * 64 + col] = fmaxf(pooled[(size_t)(r0 + rl) * 64 + col], 0.f);
    }
    __syncthreads();

    float wreg[64];
#pragma unroll
    for (int k = 0; k < 64; ++k) wreg[k] = w_l1[k * 64 + col];
    float bs = b_l1[col];

    for (int i = 0; i < 16; ++i) {
        int rl = rg * 16 + i;
        const float4* xs4 = (const float4*)(Xs + rl * 64);
        float acc = bs;
#pragma unroll
        for (int k4 = 0; k4 < 16; ++k4) {
            float4 xv = xs4[k4];
            acc += xv.x * wreg[4 * k4] + xv.y * wreg[4 * k4 + 1] +
                   xv.z * wreg[4 * k4 + 2] + xv.w * wreg[4 * k4 + 3];
        }
        Ys[rl * 65 + col] = fmaxf(acc, 0.f);
    }
    __syncthreads();

    for (int idx = t; idx < 64 * NCLS; idx += 256) {
        int row = idx / NCLS, j = idx - row * NCLS;
        float acc = b_l2[j];
#pragma unroll
        for (int k = 0; k < 64; ++k) acc += Ys[row * 65 + k] * w_l2[k * NCLS + j];
        out[(size_t)(r0 + row) * NCLS + j] = acc;
    }
}

// ---------------------------------------------------------------------------
extern "C" void kernel_launch(void* const* d_in, const int* in_sizes, int n_in,
                              void* d_out, int out_size, void* d_ws, size_t ws_size,
                              hipStream_t stream) {
    const float* x         = (const float*)d_in[0];
    const float* edge_attr = (const float*)d_in[1];
    const int*   paths2    = (const int*)d_in[2];
    const int*   ei2       = (const int*)d_in[3];
    const int*   paths3    = (const int*)d_in[4];
    const int*   ei3       = (const int*)d_in[5];
    const int*   batch     = (const int*)d_in[6];
    const float* w_feat    = (const float*)d_in[7];
    const float* b_feat    = (const float*)d_in[8];
    const float* w_bond    = (const float*)d_in[9];
    const float* b_bond    = (const float*)d_in[10];
    const float* w_ih      = (const float*)d_in[11];
    const float* w_hh      = (const float*)d_in[12];
    const float* b_ih      = (const float*)d_in[13];
    const float* b_hh      = (const float*)d_in[14];
    const float* bn_g      = (const float*)d_in[15];
    const float* bn_b      = (const float*)d_in[16];
    const float* mlp_w1    = (const float*)d_in[17];
    const float* mlp_b1    = (const float*)d_in[18];
    const float* bn1_g     = (const float*)d_in[19];
    const float* bn1_b     = (const float*)d_in[20];
    const float* mlp_w2    = (const float*)d_in[21];
    const float* mlp_b2    = (const float*)d_in[22];
    const float* bn2_g     = (const float*)d_in[23];
    const float* bn2_b     = (const float*)d_in[24];
    const float* w_att     = (const float*)d_in[25];
    const float* b_att     = (const float*)d_in[26];
    const float* w_l1      = (const float*)d_in[27];
    const float* b_l1      = (const float*)d_in[28];
    const float* w_l2      = (const float*)d_in[29];
    const float* b_l2      = (const float*)d_in[30];

    const size_t N64 = (size_t)NNODES * 64;
    float* ws = (float*)d_ws;
    float* W0     = ws;
    float* W1     = W0 + N64;
    float* W2     = W1 + N64;
    float* Wtmp   = W2 + N64;
    float* hsum1  = Wtmp + N64;
    float* hsum2  = hsum1 + N64;
    unsigned short* W0b  = (unsigned short*)(hsum2 + N64);
    unsigned short* Winb = W0b + N64;
    unsigned short* eab  = Winb + N64;
    unsigned short* Bp   = eab + (size_t)NEDGES * 64;
    float* bsum   = (float*)(Bp + 6 * 16 * 64 * 8);
    float* st     = bsum + 256;
    float* atts   = st + 6 * 128;
    float* watt   = atts + 128;
    float* pooled = watt + 64;
    float* outp   = (float*)d_out;

    // single fused prep: encode + Bp + bsum + zero(st/atts/watt, hsum1+hsum2, pooled)
    prep_encode<<<NB_ENC + 193 + 3200 + 512, 256, 0, stream>>>(
        x, w_feat, b_feat, edge_attr, w_bond, b_bond, W0, W0b, eab,
        w_ih, w_hh, b_ih, b_hh, Bp, bsum, st, hsum1, pooled);

    // ---------------- conv 1 (L=2) ----------------
    conv_mfma<2><<<(NP2 + 63) / 64, 256, 0, stream>>>(W0b, eab, paths2, ei2, Bp, bsum, hsum1, NP2);

    col_stats<<<1024, 256, 0, stream>>>(hsum1, NNODES, st + 0);
    gemm64<false, true><<<(NNODES + 63) / 64, 256, 0, stream>>>(hsum1, st + 0, bn_g + 0, bn_b + 0, mlp_w1, mlp_b1, Wtmp, st + 128, NNODES);
    gemm64<true, true><<<(NNODES + 63) / 64, 256, 0, stream>>>(Wtmp, st + 128, bn1_g + 0, bn1_b + 0, mlp_w2, mlp_b2, W1, st + 256, NNODES);
    bn_apply1<<<(int)((N64 / 4 + 255) / 256), 256, 0, stream>>>(W1, st + 256, bn2_g + 0, bn2_b + 0, W0, Winb, NNODES);

    // ---------------- conv 2 (L=3) ----------------
    conv_mfma<3><<<(NP3 + 63) / 64, 256, 0, stream>>>(Winb, eab, paths3, ei3, Bp, bsum, hsum2, NP3);

    col_stats<<<1024, 256, 0, stream>>>(hsum2, NNODES, st + 384);
    gemm64<false, true><<<(NNODES + 63) / 64, 256, 0, stream>>>(hsum2, st + 384, bn_g + 64, bn_b + 64, mlp_w1 + 4096, mlp_b1 + 64, Wtmp, st + 512, NNODES);
    gemm64<true, true><<<(NNODES + 63) / 64, 256, 0, stream>>>(Wtmp, st + 512, bn1_g + 64, bn1_b + 64, mlp_w2 + 4096, mlp_b2 + 64, W2, st + 640, NNODES);
    bn_apply_att<<<1024, 256, 0, stream>>>(W2, st + 640, bn2_g + 64, bn2_b + 64, W0, W1, atts, NNODES);

    // ---------------- attention + pooling + head ----------------
    pool_rep<<<(NNODES + PROWS - 1) / PROWS, 256, 0, stream>>>(W0, W1, W2, atts, w_att, b_att, batch, pooled, NNODES);
    head_kernel<<<NG / 64, 256, 0, stream>>>(pooled, w_l1, b_l1, w_l2, b_l2, outp);
}